// Round 8
// baseline (340.365 us; speedup 1.0000x reference)
//
#include <hip/hip_runtime.h>
#include <hip/hip_cooperative_groups.h>

namespace cg = cooperative_groups;

// Geometry fixed by setup_inputs: [16, 1, 352, 1216] fp32.
#define BATCH 16
#define HH    352
#define WW    1216
#define IMG   (HH * WW)
#define QPR   (WW / 4)           // 304 quads (float4 groups) per row
#define RPB   8                  // output rows per wave
#define NROW  (RPB + 2)          // 10 input rows per tensor
#define RQI   (HH / RPB)         // 44 row-strips per image
#define CWPR  5                  // column-waves per row (5*64 quads >= 304)
#define SPI   (RQI * CWPR)       // 220 wave-slots per image
#define SPAD  256                // padded to 4*64 (pads zero-filled)
#define WPB   4                  // waves per block
#define BLOCK (WPB * 64)         // 256 threads
#define NWAVES (BATCH * SPI)     // 3520
#define NBLK  (NWAVES / WPB)     // 880 (<= 1024 co-resident at 4 waves/SIMD)
#define NXCD  8
#define CHUNK (NBLK / NXCD)      // 110

// Workspace (floats): [0 .. 16383] p1s = float4[16*256] {Sm,Sp,St,0};
//                     [16384 .. 20479] acc = float[16*256] loss partials.
#define WS_ACC_F (BATCH * SPAD * 4)

__device__ __forceinline__ float med3f(float a, float b, float c) {
#if defined(__has_builtin) && __has_builtin(__builtin_amdgcn_fmed3f)
    return __builtin_amdgcn_fmed3f(a, b, c);
#else
    return fmaxf(fminf(fmaxf(a, b), c), fminf(a, b));
#endif
}

// Bijective XCD swizzle (880 % 8 == 0): contiguous strips share an XCD's L2.
__device__ __forceinline__ int swz(int i) {
    return (i & (NXCD - 1)) * CHUNK + (i >> 3);
}

__device__ __forceinline__ float4 load4(const float* __restrict__ img, int h,
                                        int c0) {
    const int hc = min(max(h, 0), HH - 1);
    return *reinterpret_cast<const float4*>(img + hc * WW + c0);
}

// Assemble one 6-wide row: in-wave halos via shfl; wave-boundary halos via
// broadcast of the 20-lane halo gather. No LDS, no block barrier.
__device__ __forceinline__ void mkrow(const float4 v, float halo, int r,
                                      int lane, bool lz, bool rz,
                                      float (&W)[6]) {
    float vL = __shfl_up(v.w, 1, 64);
    float vR = __shfl_down(v.x, 1, 64);
    float hL = __shfl(halo, r, 64);          // lane r: left halo, row r
    float hR = __shfl(halo, r + NROW, 64);   // lane r+NROW: right halo
    W[0] = lz ? 0.f : ((lane == 0)  ? hL : vL);
    W[1] = v.x; W[2] = v.y; W[3] = v.z; W[4] = v.w;
    W[5] = rz ? 0.f : ((lane == 63) ? hR : vR);
}

// Contrast (center - exact 3x3 median) for an 8-row strip of one tensor.
// Loads its own 10 quads + 1 halo gather, all in flight before compute;
// rolling 3-row window keeps register liveness low.
__device__ __forceinline__ void contrast_strip(const float* __restrict__ img,
                                               int h0, int c0, int cw, int lane,
                                               bool lz, bool rz, bool topz,
                                               bool botz, float (&c)[RPB][4]) {
    float4 v[NROW];
#pragma unroll
    for (int r = 0; r < NROW; ++r) v[r] = load4(img, h0 - 1 + r, c0);
    float halo = 0.f;
    if (lane < 2 * NROW) {                 // 20-lane halo column gather
        const int r   = (lane < NROW) ? lane : lane - NROW;
        const int hc  = min(max(h0 - 1 + r, 0), HH - 1);
        const int col = (lane < NROW) ? max(cw * 256 - 1, 0)
                                      : min(cw * 256 + 256, WW - 1);
        halo = img[hc * WW + col];
    }
    __builtin_amdgcn_sched_barrier(0);     // all 11 loads issued before compute

    float A[6], B[6], C[6];
    mkrow(v[0], halo, 0, lane, lz, rz, A);
    if (topz) {
#pragma unroll
        for (int j = 0; j < 6; ++j) A[j] = 0.f;
    }
    mkrow(v[1], halo, 1, lane, lz, rz, B);
#pragma unroll
    for (int t = 0; t < RPB; ++t) {
        mkrow(v[t + 2], halo, t + 2, lane, lz, rz, C);
        if (botz && t == RPB - 1) {
#pragma unroll
            for (int j = 0; j < 6; ++j) C[j] = 0.f;
        }
        float lo[6], mi[6], hi[6];
#pragma unroll
        for (int j = 0; j < 6; ++j) {
            lo[j] = fminf(fminf(A[j], B[j]), C[j]);
            hi[j] = fmaxf(fmaxf(A[j], B[j]), C[j]);
            mi[j] = med3f(A[j], B[j], C[j]);
        }
#pragma unroll
        for (int i = 0; i < 4; ++i) {
            float mx = fmaxf(fmaxf(lo[i], lo[i + 1]), lo[i + 2]);
            float md = med3f(mi[i], mi[i + 1], mi[i + 2]);
            float mn = fminf(fminf(hi[i], hi[i + 1]), hi[i + 2]);
            c[t][i] = B[i + 1] - med3f(mx, md, mn);
        }
#pragma unroll
        for (int j = 0; j < 6; ++j) { A[j] = B[j]; B[j] = C[j]; }
    }
}

__device__ __forceinline__ float waveRed(float v) {
#pragma unroll
    for (int o = 32; o > 0; o >>= 1) v += __shfl_down(v, o, 64);
    return v;
}

// ---------- fused cooperative kernel: pass1 + grid.sync + pass2 + finalize ----
// pc/tc are HELD IN REGISTERS across the grid sync: pass2 re-reads nothing.
__global__ __launch_bounds__(BLOCK, 4) void fused(const float* __restrict__ pred,
                                                  const float* __restrict__ tgt,
                                                  const float* __restrict__ mask,
                                                  float4* __restrict__ p1s4,
                                                  float* __restrict__ acc,
                                                  float* __restrict__ out) {
    const int wid = threadIdx.x >> 6, lane = threadIdx.x & 63;
    const int g   = swz(blockIdx.x) * WPB + wid;
    const int rq  = g / CWPR, cw = g - rq * CWPR;
    const int b   = rq / RQI, rb = rq - b * RQI;
    const int h0  = rb * RPB;
    const int gq  = cw * 64 + lane;
    const int c0  = min(gq * 4, WW - 4);
    const bool qv = gq < QPR;
    const bool lz = (c0 == 0), rz = (c0 + 4 >= WW);
    const bool topz = (rb == 0), botz = (rb == RQI - 1);
    const int s   = rb * CWPR + cw;

    const float* pimg = pred + b * IMG;
    const float* timg = tgt  + b * IMG;

    float pc[RPB][4], tc[RPB][4];
    contrast_strip(pimg, h0, c0, cw, lane, lz, rz, topz, botz, pc);
    contrast_strip(timg, h0, c0, cw, lane, lz, rz, topz, botz, tc);

    const float* mrow = mask + b * IMG + h0 * WW + c0;
    float s_m = 0.f, s_p = 0.f, s_t = 0.f;
#pragma unroll
    for (int r = 0; r < RPB; ++r) {
        float4 m4 = *reinterpret_cast<const float4*>(mrow + r * WW);
        float mv[4] = {m4.x, m4.y, m4.z, m4.w};
#pragma unroll
        for (int k = 0; k < 4; ++k) {
            s_m += mv[k];
            s_p += mv[k] * fabsf(pc[r][k]);
            s_t += mv[k] * fabsf(tc[r][k]);
        }
    }
    if (!qv) { s_m = 0.f; s_p = 0.f; s_t = 0.f; }
    s_m = waveRed(s_m); s_p = waveRed(s_p); s_t = waveRed(s_t);
    if (lane == 0) {
        p1s4[b * SPAD + s] = make_float4(s_m, s_p, s_t, 0.f);
        if (s < SPAD - SPI)                 // zero the 36 pad slots per image
            p1s4[b * SPAD + SPI + s] = make_float4(0.f, 0.f, 0.f, 0.f);
    }

    cg::this_grid().sync();

    // Per-wave redundant fold of this image's 256 slots (L2-hot).
    const float4* s4 = p1s4 + b * SPAD;
    float4 f0 = s4[lane], f1 = s4[lane + 64], f2 = s4[lane + 128],
           f3 = s4[lane + 192];
    float sm = f0.x + f1.x + f2.x + f3.x;
    float sp = f0.y + f1.y + f2.y + f3.y;
    float st = f0.z + f1.z + f2.z + f3.z;
#pragma unroll
    for (int o = 32; o > 0; o >>= 1) {
        sm += __shfl_xor(sm, o, 64);
        sp += __shfl_xor(sp, o, 64);
        st += __shfl_xor(st, o, 64);
    }
    const float inv_mp = sm / sp, inv_mt = sm / st;

    float ls = 0.f;
#pragma unroll
    for (int r = 0; r < RPB; ++r)
#pragma unroll
        for (int k = 0; k < 4; ++k)
            ls += fabsf(pc[r][k] * inv_mp - tc[r][k] * inv_mt);
    if (!qv) ls = 0.f;
    ls = waveRed(ls);
    if (lane == 0) {
        acc[b * SPAD + s] = ls;
        if (s < SPAD - SPI) acc[b * SPAD + SPI + s] = 0.f;
    }

    cg::this_grid().sync();

    if (blockIdx.x == 0) {                  // finalize: 256 threads
        const int t = threadIdx.x;
        float tm = 0.f, ta = 0.f;
#pragma unroll
        for (int k = 0; k < BATCH; ++k) {
            tm += p1s4[t + k * SPAD].x;
            ta += acc[t + k * SPAD];
        }
        tm = waveRed(tm); ta = waveRed(ta);
        __shared__ float r0[WPB], r1[WPB];
        if (lane == 0) { r0[wid] = tm; r1[wid] = ta; }
        __syncthreads();
        if (t == 0) {
            float m = 0.f, a = 0.f;
#pragma unroll
            for (int w = 0; w < WPB; ++w) { m += r0[w]; a += r1[w]; }
            out[0] = a / m;
        }
    }
}

// ---------- non-cooperative fallback (used iff coop launch errors) ----------
__global__ __launch_bounds__(BLOCK, 4) void pass1_fb(const float* __restrict__ pred,
                                                     const float* __restrict__ tgt,
                                                     const float* __restrict__ mask,
                                                     float4* __restrict__ p1s4) {
    const int wid = threadIdx.x >> 6, lane = threadIdx.x & 63;
    const int g   = swz(blockIdx.x) * WPB + wid;
    const int rq  = g / CWPR, cw = g - rq * CWPR;
    const int b   = rq / RQI, rb = rq - b * RQI;
    const int h0  = rb * RPB;
    const int gq  = cw * 64 + lane;
    const int c0  = min(gq * 4, WW - 4);
    const bool qv = gq < QPR;
    const bool lz = (c0 == 0), rz = (c0 + 4 >= WW);
    const bool topz = (rb == 0), botz = (rb == RQI - 1);
    const int s   = rb * CWPR + cw;

    float pc[RPB][4], tc[RPB][4];
    contrast_strip(pred + b * IMG, h0, c0, cw, lane, lz, rz, topz, botz, pc);
    contrast_strip(tgt  + b * IMG, h0, c0, cw, lane, lz, rz, topz, botz, tc);

    const float* mrow = mask + b * IMG + h0 * WW + c0;
    float s_m = 0.f, s_p = 0.f, s_t = 0.f;
#pragma unroll
    for (int r = 0; r < RPB; ++r) {
        float4 m4 = *reinterpret_cast<const float4*>(mrow + r * WW);
        float mv[4] = {m4.x, m4.y, m4.z, m4.w};
#pragma unroll
        for (int k = 0; k < 4; ++k) {
            s_m += mv[k];
            s_p += mv[k] * fabsf(pc[r][k]);
            s_t += mv[k] * fabsf(tc[r][k]);
        }
    }
    if (!qv) { s_m = 0.f; s_p = 0.f; s_t = 0.f; }
    s_m = waveRed(s_m); s_p = waveRed(s_p); s_t = waveRed(s_t);
    if (lane == 0) {
        p1s4[b * SPAD + s] = make_float4(s_m, s_p, s_t, 0.f);
        if (s < SPAD - SPI)
            p1s4[b * SPAD + SPI + s] = make_float4(0.f, 0.f, 0.f, 0.f);
    }
}

__global__ __launch_bounds__(BLOCK, 4) void pass2_fb(const float* __restrict__ pred,
                                                     const float* __restrict__ tgt,
                                                     const float4* __restrict__ p1s4,
                                                     float* __restrict__ acc) {
    const int wid = threadIdx.x >> 6, lane = threadIdx.x & 63;
    const int g   = swz(blockIdx.x) * WPB + wid;
    const int rq  = g / CWPR, cw = g - rq * CWPR;
    const int b   = rq / RQI, rb = rq - b * RQI;
    const int h0  = rb * RPB;
    const int gq  = cw * 64 + lane;
    const int c0  = min(gq * 4, WW - 4);
    const bool qv = gq < QPR;
    const bool lz = (c0 == 0), rz = (c0 + 4 >= WW);
    const bool topz = (rb == 0), botz = (rb == RQI - 1);
    const int s   = rb * CWPR + cw;

    const float4* s4 = p1s4 + b * SPAD;
    float4 f0 = s4[lane], f1 = s4[lane + 64], f2 = s4[lane + 128],
           f3 = s4[lane + 192];
    float sm = f0.x + f1.x + f2.x + f3.x;
    float sp = f0.y + f1.y + f2.y + f3.y;
    float st = f0.z + f1.z + f2.z + f3.z;
#pragma unroll
    for (int o = 32; o > 0; o >>= 1) {
        sm += __shfl_xor(sm, o, 64);
        sp += __shfl_xor(sp, o, 64);
        st += __shfl_xor(st, o, 64);
    }
    const float inv_mp = sm / sp, inv_mt = sm / st;

    float pc[RPB][4], tc[RPB][4];
    contrast_strip(pred + b * IMG, h0, c0, cw, lane, lz, rz, topz, botz, pc);
    contrast_strip(tgt  + b * IMG, h0, c0, cw, lane, lz, rz, topz, botz, tc);

    float ls = 0.f;
#pragma unroll
    for (int r = 0; r < RPB; ++r)
#pragma unroll
        for (int k = 0; k < 4; ++k)
            ls += fabsf(pc[r][k] * inv_mp - tc[r][k] * inv_mt);
    if (!qv) ls = 0.f;
    ls = waveRed(ls);
    if (lane == 0) {
        acc[b * SPAD + s] = ls;
        if (s < SPAD - SPI) acc[b * SPAD + SPI + s] = 0.f;
    }
}

__global__ __launch_bounds__(BLOCK) void fin_fb(const float4* __restrict__ p1s4,
                                                const float* __restrict__ acc,
                                                float* __restrict__ out) {
    const int t = threadIdx.x, lane = t & 63, wid = t >> 6;
    float tm = 0.f, ta = 0.f;
#pragma unroll
    for (int k = 0; k < BATCH; ++k) {
        tm += p1s4[t + k * SPAD].x;
        ta += acc[t + k * SPAD];
    }
    tm = waveRed(tm); ta = waveRed(ta);
    __shared__ float r0[WPB], r1[WPB];
    if (lane == 0) { r0[wid] = tm; r1[wid] = ta; }
    __syncthreads();
    if (t == 0) {
        float m = 0.f, a = 0.f;
#pragma unroll
        for (int w = 0; w < WPB; ++w) { m += r0[w]; a += r1[w]; }
        out[0] = a / m;
    }
}

extern "C" void kernel_launch(void* const* d_in, const int* in_sizes, int n_in,
                              void* d_out, int out_size, void* d_ws, size_t ws_size,
                              hipStream_t stream) {
    const float* pred = (const float*)d_in[0];
    const float* tgt  = (const float*)d_in[1];
    const float* mask = (const float*)d_in[2];
    float* out = (float*)d_out;
    float* ws  = (float*)d_ws;
    float4* p1s4 = (float4*)ws;
    float*  acc  = ws + WS_ACC_F;

    void* args[6] = {(void*)&pred, (void*)&tgt, (void*)&mask,
                     (void*)&p1s4, (void*)&acc, (void*)&out};
    hipError_t e = hipLaunchCooperativeKernel((const void*)fused, dim3(NBLK),
                                              dim3(BLOCK), args, 0, stream);
    if (e != hipSuccess) {
        // Fallback: 3-kernel path, stream-ordered (no fences anywhere).
        pass1_fb<<<dim3(NBLK), dim3(BLOCK), 0, stream>>>(pred, tgt, mask, p1s4);
        pass2_fb<<<dim3(NBLK), dim3(BLOCK), 0, stream>>>(pred, tgt, p1s4, acc);
        fin_fb<<<1, dim3(BLOCK), 0, stream>>>(p1s4, acc, out);
    }
}

// Round 9
// 202.702 us; speedup vs baseline: 1.6791x; 1.6791x over previous
//
#include <hip/hip_runtime.h>

// Geometry fixed by setup_inputs: [16, 1, 352, 1216] fp32.
#define BATCH 16
#define HH    352
#define WW    1216
#define IMG   (HH * WW)
#define QPR   (WW / 4)       // 304 quads per row
#define RPB   4              // output rows per task
#define NROW  (RPB + 2)      // 6 input rows per task
#define RQI   (HH / RPB)     // 88 row-strips per image
#define CWPR  5              // column-waves per row (5*64 >= 304)
#define TPI   (RQI * CWPR)   // 440 tasks per image
#define TPW   4              // tasks per wave
#define WPI   (TPI / TPW)    // 110 waves per image (exact)
#define NWAVE (BATCH * WPI)  // 1760
#define WPB   4              // waves per block
#define BLOCK 256
#define NBLK  (NWAVE / WPB)  // 440  (<= 1024 guaranteed-resident at 4 wv/SIMD)

// Workspace (floats): [b*4 + {0,1,2}] = {Sm,Sp,St} per image; [64] = loss;
// [66],[67] = arrival counters (uint). All zeroed by a 512 B memset.
#define WS_LOSS 64
#define WS_CTR  66

__device__ __forceinline__ float med3f(float a, float b, float c) {
#if defined(__has_builtin) && __has_builtin(__builtin_amdgcn_fmed3f)
    return __builtin_amdgcn_fmed3f(a, b, c);
#else
    return fmaxf(fminf(fmaxf(a, b), c), fminf(a, b));
#endif
}

__device__ __forceinline__ float4 load4(const float* __restrict__ img, int h,
                                        int c0) {
    const int hc = min(max(h, 0), HH - 1);
    return *reinterpret_cast<const float4*>(img + hc * WW + c0);
}

struct TaskLoad { float4 v[NROW]; float halo; };

// Issue one tensor's task loads: 6 coalesced quads + a 12-lane halo gather.
__device__ __forceinline__ void issue(const float* __restrict__ img, int h0,
                                      int c0, int cw, int lane, TaskLoad& L) {
#pragma unroll
    for (int r = 0; r < NROW; ++r) L.v[r] = load4(img, h0 - 1 + r, c0);
    L.halo = 0.f;
    if (lane < 2 * NROW) {
        const int r   = (lane < NROW) ? lane : lane - NROW;
        const int hc  = min(max(h0 - 1 + r, 0), HH - 1);
        const int col = (lane < NROW) ? max(cw * 256 - 1, 0)
                                      : min(cw * 256 + 256, WW - 1);
        L.halo = img[hc * WW + col];
    }
}

// Assemble 6 six-wide rows (in-wave shfl halos + gathered wave-boundary
// halos; zero padding at image edges). No LDS, no block barrier.
__device__ __forceinline__ void mkwin6(const TaskLoad& L, int lane, bool lz,
                                       bool rz, bool topz, bool botz,
                                       float (&W)[NROW][6]) {
#pragma unroll
    for (int r = 0; r < NROW; ++r) {
        float vL = __shfl_up(L.v[r].w, 1, 64);
        float vR = __shfl_down(L.v[r].x, 1, 64);
        float hL = __shfl(L.halo, r, 64);
        float hR = __shfl(L.halo, r + NROW, 64);
        W[r][0] = lz ? 0.f : ((lane == 0)  ? hL : vL);
        W[r][1] = L.v[r].x; W[r][2] = L.v[r].y;
        W[r][3] = L.v[r].z; W[r][4] = L.v[r].w;
        W[r][5] = rz ? 0.f : ((lane == 63) ? hR : vR);
    }
    if (topz) {
#pragma unroll
        for (int j = 0; j < 6; ++j) W[0][j] = 0.f;
    }
    if (botz) {
#pragma unroll
        for (int j = 0; j < 6; ++j) W[NROW - 1][j] = 0.f;
    }
}

// contrast = center - exact 3x3 median (min3/med3/max3 network).
__device__ __forceinline__ void contrast4x4(const float (&W)[NROW][6],
                                            float (&c)[RPB][4]) {
#pragma unroll
    for (int t = 0; t < RPB; ++t) {
        float lo[6], mi[6], hi[6];
#pragma unroll
        for (int j = 0; j < 6; ++j) {
            lo[j] = fminf(fminf(W[t][j], W[t + 1][j]), W[t + 2][j]);
            hi[j] = fmaxf(fmaxf(W[t][j], W[t + 1][j]), W[t + 2][j]);
            mi[j] = med3f(W[t][j], W[t + 1][j], W[t + 2][j]);
        }
#pragma unroll
        for (int i = 0; i < 4; ++i) {
            float mx = fmaxf(fmaxf(lo[i], lo[i + 1]), lo[i + 2]);
            float md = med3f(mi[i], mi[i + 1], mi[i + 2]);
            float mn = fminf(fminf(hi[i], hi[i + 1]), hi[i + 2]);
            c[t][i] = W[t + 1][i + 1] - med3f(mx, md, mn);
        }
    }
}

__device__ __forceinline__ float waveRed(float v) {
#pragma unroll
    for (int o = 32; o > 0; o >>= 1) v += __shfl_down(v, o, 64);
    return v;
}

// Single fused kernel. Cross-block communication is EXCLUSIVELY atomic RMWs
// (device-coherent at the coherence point) -> no fences, no L2 flush storm.
// 440 blocks @ launch_bounds(256,4) are guaranteed co-resident (<=1024 slots).
__global__ __launch_bounds__(BLOCK, 4) void fused(const float* __restrict__ pred,
                                                  const float* __restrict__ tgt,
                                                  const float* __restrict__ mask,
                                                  float* __restrict__ ws,
                                                  float* __restrict__ out) {
    const int wid = threadIdx.x >> 6, lane = threadIdx.x & 63;
    const int w   = blockIdx.x * WPB + wid;   // global wave id
    const int b   = w / WPI;                  // image (all 4 tasks same image)
    const int lw  = w - b * WPI;

    const float* pimg = pred + b * IMG;
    const float* timg = tgt  + b * IMG;
    const float* mimg = mask + b * IMG;
    float* sums = ws + b * 4;
    unsigned* ctr = reinterpret_cast<unsigned*>(ws + WS_CTR);

    // ---------------- phase 1: per-image {Sm, Sp, St} ----------------
    float s_m = 0.f, s_p = 0.f, s_t = 0.f;
    for (int t = 0; t < TPW; ++t) {
        const int tau = lw * TPW + t;
        const int rq = tau / CWPR, cw = tau - rq * CWPR;
        const int h0 = rq * RPB;
        const int gq = cw * 64 + lane;
        const int c0 = min(gq * 4, WW - 4);
        const bool qv = gq < QPR;
        const bool lz = (c0 == 0), rz = (c0 + 4 >= WW);
        const bool topz = (rq == 0), botz = (rq == RQI - 1);

        TaskLoad P, T;
        float4 m4[RPB];
        issue(pimg, h0, c0, cw, lane, P);
        issue(timg, h0, c0, cw, lane, T);
        const float* mrow = mimg + h0 * WW + c0;
#pragma unroll
        for (int r = 0; r < RPB; ++r)
            m4[r] = *reinterpret_cast<const float4*>(mrow + r * WW);
        __builtin_amdgcn_sched_barrier(0);   // all 16 loads in flight

        float W[NROW][6], pc[RPB][4], tc[RPB][4];
        mkwin6(P, lane, lz, rz, topz, botz, W);
        contrast4x4(W, pc);
        mkwin6(T, lane, lz, rz, topz, botz, W);
        contrast4x4(W, tc);

#pragma unroll
        for (int r = 0; r < RPB; ++r) {
            float mv[4] = {m4[r].x, m4[r].y, m4[r].z, m4[r].w};
#pragma unroll
            for (int k = 0; k < 4; ++k) {
                float m = qv ? mv[k] : 0.f;
                s_m += m;
                s_p += m * fabsf(pc[r][k]);
                s_t += m * fabsf(tc[r][k]);
            }
        }
    }
    s_m = waveRed(s_m); s_p = waveRed(s_p); s_t = waveRed(s_t);
    if (lane == 0) {
        atomicAdd(&sums[0], s_m);
        atomicAdd(&sums[1], s_p);
        atomicAdd(&sums[2], s_t);
    }
    // Drain THIS wave's atomics to the coherence point, then block-arrive.
    asm volatile("s_waitcnt vmcnt(0)" ::: "memory");
    __syncthreads();
    if (threadIdx.x == 0) {
        atomicAdd(&ctr[0], 1u);
        while (atomicAdd(&ctr[0], 0u) < (unsigned)NBLK)  // coherent RMW poll
            __builtin_amdgcn_s_sleep(8);
    }
    __syncthreads();

    // ---------------- phase 2: loss, data re-read from own XCD's L2 -------
    float inv_mp, inv_mt;
    {
        float Sm = 0.f, Sp = 1.f, St = 1.f;
        if (lane == 0) {                       // coherent atomic reads
            Sm = atomicAdd(&sums[0], 0.f);
            Sp = atomicAdd(&sums[1], 0.f);
            St = atomicAdd(&sums[2], 0.f);
        }
        inv_mp = __shfl(Sm / Sp, 0, 64);
        inv_mt = __shfl(Sm / St, 0, 64);
    }

    float ls = 0.f;
    for (int t = 0; t < TPW; ++t) {
        const int tau = lw * TPW + t;
        const int rq = tau / CWPR, cw = tau - rq * CWPR;
        const int h0 = rq * RPB;
        const int gq = cw * 64 + lane;
        const int c0 = min(gq * 4, WW - 4);
        const bool qv = gq < QPR;
        const bool lz = (c0 == 0), rz = (c0 + 4 >= WW);
        const bool topz = (rq == 0), botz = (rq == RQI - 1);

        TaskLoad P, T;
        issue(pimg, h0, c0, cw, lane, P);
        issue(timg, h0, c0, cw, lane, T);
        __builtin_amdgcn_sched_barrier(0);

        float W[NROW][6], pc[RPB][4], tc[RPB][4];
        mkwin6(P, lane, lz, rz, topz, botz, W);
        contrast4x4(W, pc);
        mkwin6(T, lane, lz, rz, topz, botz, W);
        contrast4x4(W, tc);

        float a = 0.f;
#pragma unroll
        for (int r = 0; r < RPB; ++r)
#pragma unroll
            for (int k = 0; k < 4; ++k)
                a += fabsf(pc[r][k] * inv_mp - tc[r][k] * inv_mt);
        if (qv) ls += a;
    }
    ls = waveRed(ls);

    // Block-reduce loss -> ONE atomicAdd per block (440 adds to one address).
    __shared__ float lred[WPB];
    if (lane == 0) lred[wid] = ls;
    __syncthreads();
    if (threadIdx.x == 0) {
        float a = lred[0] + lred[1] + lred[2] + lred[3];
        atomicAdd(&ws[WS_LOSS], a);
        asm volatile("s_waitcnt vmcnt(0)" ::: "memory");
        unsigned old = atomicAdd(&ctr[1], 1u);
        if (old == (unsigned)(NBLK - 1)) {     // last block: finalize
            float tl = atomicAdd(&ws[WS_LOSS], 0.f);
            float tm = 0.f;
            for (int k = 0; k < BATCH; ++k) tm += atomicAdd(&ws[k * 4], 0.f);
            out[0] = tl / tm;
        }
    }
}

extern "C" void kernel_launch(void* const* d_in, const int* in_sizes, int n_in,
                              void* d_out, int out_size, void* d_ws, size_t ws_size,
                              hipStream_t stream) {
    const float* pred = (const float*)d_in[0];
    const float* tgt  = (const float*)d_in[1];
    const float* mask = (const float*)d_in[2];
    float* out = (float*)d_out;
    float* ws  = (float*)d_ws;

    hipMemsetAsync(d_ws, 0, 512, stream);   // zero sums/loss/counters

    fused<<<dim3(NBLK), dim3(BLOCK), 0, stream>>>(pred, tgt, mask, ws, out);
}

// Round 10
// 119.824 us; speedup vs baseline: 2.8405x; 1.6917x over previous
//
#include <hip/hip_runtime.h>

// Geometry fixed by setup_inputs: [16, 1, 352, 1216] fp32.
// Round-10 note: this is the round-7 kernel (measured best: 121.0 us),
// restored after both fusion experiments regressed (r8 coop: 340, r9
// atomic-barrier: 202). Budget model: dur_us = ~82 us (two 256 MiB harness
// workspace-poison fills) + ~39 us controllable (pass1 ~19, pass2 ~13,
// finalize+gaps ~6) vs a ~26-30 us memory-compulsory floor.
#define BATCH 16
#define HH    352
#define WW    1216
#define IMG   (HH * WW)
#define QPR   (WW / 4)          // 304 quads (float4 groups) per row
#define RPB   4                 // output rows per wave
#define NROW  (RPB + 2)         // 6 input rows per tensor
#define RQI   (HH / RPB)        // 88 row-quads per image
#define CWPR  5                 // column-waves per row (5*64 quads >= 304)
#define SPI   (RQI * CWPR)      // 440 wave-slots per image
#define SPAD  448               // padded to 7*64 (pads zero-filled)
#define WPB   4                 // waves per block (fully independent waves)
#define BLOCK (WPB * 64)
#define NWAVES (BATCH * SPI)    // 7040
#define NBLK  (NWAVES / WPB)    // 1760 (divisible by 8)
#define NXCD  8
#define CHUNK (NBLK / NXCD)     // 220

// Workspace (floats): [0 .. 28671] p1s = float4[16*448] {Sm,Sp,St,0};
//                     [28672 .. 35839] acc = float[16*448] loss partials.
#define WS_ACC_F (BATCH * SPAD * 4)

__device__ __forceinline__ float med3f(float a, float b, float c) {
#if defined(__has_builtin) && __has_builtin(__builtin_amdgcn_fmed3f)
    return __builtin_amdgcn_fmed3f(a, b, c);
#else
    return fmaxf(fminf(fmaxf(a, b), c), fminf(a, b));
#endif
}

// Bijective XCD swizzle: HW assigns block i to XCD i%8, so
// i -> (i%8)*CHUNK + i/8 gives each XCD a contiguous run of row-quads.
__device__ __forceinline__ int swz(int i) {
    return (i & (NXCD - 1)) * CHUNK + (i >> 3);
}

// One coalesced float4 per row segment (row-clamped; edges zeroed later).
__device__ __forceinline__ float4 load4(const float* __restrict__ img, int h,
                                        int c0) {
    const int hc = min(max(h, 0), HH - 1);
    return *reinterpret_cast<const float4*>(img + hc * WW + c0);
}

// Assemble 6 six-wide rows: in-wave halos via shfl_up/down; wave-boundary
// halos via broadcast shuffles of the 12-lane halo gather register.
// NO LDS, NO barrier — waves stay fully independent.
__device__ __forceinline__ void mkwin(const float4 (&v)[NROW], float halo,
                                      int lane, bool lz, bool rz,
                                      bool topz, bool botz,
                                      float (&W)[NROW][6]) {
#pragma unroll
    for (int r = 0; r < NROW; ++r) {
        float vL = __shfl_up(v[r].w, 1, 64);    // left neighbor's col3
        float vR = __shfl_down(v[r].x, 1, 64);  // right neighbor's col0
        float hL = __shfl(halo, r, 64);         // lane r holds left halo row r
        float hR = __shfl(halo, r + 6, 64);     // lane r+6 holds right halo
        W[r][0] = lz ? 0.f : ((lane == 0)  ? hL : vL);
        W[r][1] = v[r].x; W[r][2] = v[r].y; W[r][3] = v[r].z; W[r][4] = v[r].w;
        W[r][5] = rz ? 0.f : ((lane == 63) ? hR : vR);
    }
    if (topz) {
#pragma unroll
        for (int j = 0; j < 6; ++j) W[0][j] = 0.f;
    }
    if (botz) {
#pragma unroll
        for (int j = 0; j < 6; ++j) W[NROW - 1][j] = 0.f;
    }
}

// 4 output rows of 4 contrasts from the 6 assembled rows (exact 3x3 median).
__device__ __forceinline__ void contrast4x4(const float (&W)[NROW][6],
                                            float (&c)[RPB][4]) {
#pragma unroll
    for (int t = 0; t < RPB; ++t) {
        float lo[6], mi[6], hi[6];
#pragma unroll
        for (int j = 0; j < 6; ++j) {
            lo[j] = fminf(fminf(W[t][j], W[t + 1][j]), W[t + 2][j]);
            hi[j] = fmaxf(fmaxf(W[t][j], W[t + 1][j]), W[t + 2][j]);
            mi[j] = med3f(W[t][j], W[t + 1][j], W[t + 2][j]);
        }
#pragma unroll
        for (int i = 0; i < 4; ++i) {
            float mx = fmaxf(fmaxf(lo[i], lo[i + 1]), lo[i + 2]);
            float md = med3f(mi[i], mi[i + 1], mi[i + 2]);
            float mn = fminf(fminf(hi[i], hi[i + 1]), hi[i + 2]);
            c[t][i] = W[t + 1][i + 1] - med3f(mx, md, mn);
        }
    }
}

__device__ __forceinline__ float waveRed(float v) {
#pragma unroll
    for (int o = 32; o > 0; o >>= 1) v += __shfl_down(v, o, 64);
    return v;
}

// Pass 1: per-image sums of {mask, mask*|pc|, mask*|tc|}; one wave per
// (row-quad, 64-quad column span); per-wave reduce; plain store to own slot.
__global__ __launch_bounds__(BLOCK, 4) void pass1(const float* __restrict__ pred,
                                                  const float* __restrict__ tgt,
                                                  const float* __restrict__ mask,
                                                  float4* __restrict__ p1s4) {
    const int wid  = threadIdx.x >> 6, lane = threadIdx.x & 63;
    const int g    = swz(blockIdx.x) * WPB + wid;
    const int rq   = g / CWPR, cw = g - rq * CWPR;
    const int b    = rq / RQI,  rb = rq - b * RQI;
    const int h0   = rb * RPB;
    const int gq   = cw * 64 + lane;
    const int c0   = min(gq * 4, WW - 4);
    const bool qv  = gq < QPR;

    const float* pimg = pred + b * IMG;
    const float* timg = tgt  + b * IMG;

    float4 vp[NROW], vt[NROW], m4[RPB];
#pragma unroll
    for (int r = 0; r < NROW; ++r) vp[r] = load4(pimg, h0 - 1 + r, c0);
    float hp = 0.f, ht = 0.f;
    int haddr = 0;
    if (lane < 12) {                      // 12-lane halo gather (1 instr/tensor)
        const int r   = (lane < 6) ? lane : lane - 6;
        const int hc  = min(max(h0 - 1 + r, 0), HH - 1);
        const int col = (lane < 6) ? max(cw * 256 - 1, 0)
                                   : min(cw * 256 + 256, WW - 1);
        haddr = hc * WW + col;
        hp = pimg[haddr];
    }
#pragma unroll
    for (int r = 0; r < NROW; ++r) vt[r] = load4(timg, h0 - 1 + r, c0);
    if (lane < 12) ht = timg[haddr];
    const float* mrow = mask + b * IMG + h0 * WW + c0;
#pragma unroll
    for (int r = 0; r < RPB; ++r)
        m4[r] = *reinterpret_cast<const float4*>(mrow + r * WW);
    __builtin_amdgcn_sched_barrier(0);    // all loads issued before compute

    const bool lz = (c0 == 0), rz = (c0 + 4 >= WW);
    const bool topz = (rb == 0), botz = (rb == RQI - 1);

    // pred stage waits only its own loads (vmcnt partial) — tgt+mask in flight
    float W[NROW][6], pc[RPB][4], tc[RPB][4];
    mkwin(vp, hp, lane, lz, rz, topz, botz, W);
    contrast4x4(W, pc);
    mkwin(vt, ht, lane, lz, rz, topz, botz, W);
    contrast4x4(W, tc);

    float s_m = 0.f, s_p = 0.f, s_t = 0.f;
#pragma unroll
    for (int r = 0; r < RPB; ++r) {
        float mv[4] = {m4[r].x, m4[r].y, m4[r].z, m4[r].w};
#pragma unroll
        for (int k = 0; k < 4; ++k) {
            s_m += mv[k];
            s_p += mv[k] * fabsf(pc[r][k]);
            s_t += mv[k] * fabsf(tc[r][k]);
        }
    }
    if (!qv) { s_m = 0.f; s_p = 0.f; s_t = 0.f; }

    s_m = waveRed(s_m); s_p = waveRed(s_p); s_t = waveRed(s_t);

    const int s = rb * CWPR + cw;
    if (lane == 0) {
        p1s4[b * SPAD + s] = make_float4(s_m, s_p, s_t, 0.f);
        if (s < SPAD - SPI)               // zero-fill the 8 pad slots
            p1s4[b * SPAD + SPI + s] = make_float4(0.f, 0.f, 0.f, 0.f);
    }
}

// Pass 2: per-image sum of |pc*inv_mp - tc*inv_mt|. Fold loads issue FIRST
// so the per-wave p1s fold runs while the stencil loads are in flight.
__global__ __launch_bounds__(BLOCK, 4) void pass2(const float* __restrict__ pred,
                                                  const float* __restrict__ tgt,
                                                  const float4* __restrict__ p1s4,
                                                  float* __restrict__ acc) {
    const int wid  = threadIdx.x >> 6, lane = threadIdx.x & 63;
    const int g    = swz(blockIdx.x) * WPB + wid;
    const int rq   = g / CWPR, cw = g - rq * CWPR;
    const int b    = rq / RQI,  rb = rq - b * RQI;
    const int h0   = rb * RPB;
    const int gq   = cw * 64 + lane;
    const int c0   = min(gq * 4, WW - 4);
    const bool qv  = gq < QPR;

    const float4* s4 = p1s4 + b * SPAD;
    float4 fv[7];
#pragma unroll
    for (int k = 0; k < 7; ++k) fv[k] = s4[lane + k * 64];

    const float* pimg = pred + b * IMG;
    const float* timg = tgt  + b * IMG;

    float4 vp[NROW], vt[NROW];
#pragma unroll
    for (int r = 0; r < NROW; ++r) vp[r] = load4(pimg, h0 - 1 + r, c0);
    float hp = 0.f, ht = 0.f;
    int haddr = 0;
    if (lane < 12) {
        const int r   = (lane < 6) ? lane : lane - 6;
        const int hc  = min(max(h0 - 1 + r, 0), HH - 1);
        const int col = (lane < 6) ? max(cw * 256 - 1, 0)
                                   : min(cw * 256 + 256, WW - 1);
        haddr = hc * WW + col;
        hp = pimg[haddr];
    }
#pragma unroll
    for (int r = 0; r < NROW; ++r) vt[r] = load4(timg, h0 - 1 + r, c0);
    if (lane < 12) ht = timg[haddr];
    __builtin_amdgcn_sched_barrier(0);    // all loads issued before compute

    // Fold waits only the 7 oldest loads; stencil stays in flight.
    float sm = 0.f, sp = 0.f, st = 0.f;
#pragma unroll
    for (int k = 0; k < 7; ++k) { sm += fv[k].x; sp += fv[k].y; st += fv[k].z; }
#pragma unroll
    for (int o = 32; o > 0; o >>= 1) {
        sm += __shfl_xor(sm, o, 64);
        sp += __shfl_xor(sp, o, 64);
        st += __shfl_xor(st, o, 64);
    }
    const float inv_mp = sm / sp;
    const float inv_mt = sm / st;

    const bool lz = (c0 == 0), rz = (c0 + 4 >= WW);
    const bool topz = (rb == 0), botz = (rb == RQI - 1);

    float W[NROW][6], pc[RPB][4], tc[RPB][4];
    mkwin(vp, hp, lane, lz, rz, topz, botz, W);
    contrast4x4(W, pc);
    mkwin(vt, ht, lane, lz, rz, topz, botz, W);
    contrast4x4(W, tc);

    float s = 0.f;
#pragma unroll
    for (int r = 0; r < RPB; ++r)
#pragma unroll
        for (int k = 0; k < 4; ++k)
            s += fabsf(pc[r][k] * inv_mp - tc[r][k] * inv_mt);
    if (!qv) s = 0.f;

    s = waveRed(s);

    const int sl = rb * CWPR + cw;
    if (lane == 0) {
        acc[b * SPAD + sl] = s;
        if (sl < SPAD - SPI)
            acc[b * SPAD + SPI + sl] = 0.f;
    }
}

__global__ __launch_bounds__(1024) void finalize(const float4* __restrict__ p1s4,
                                                 const float* __restrict__ acc,
                                                 float* __restrict__ out) {
    float tm = 0.f, ta = 0.f;
    for (int j = threadIdx.x; j < BATCH * SPAD; j += 1024) {
        tm += p1s4[j].x;
        ta += acc[j];
    }
    tm = waveRed(tm); ta = waveRed(ta);
    __shared__ float r0[16], r1[16];
    const int lane = threadIdx.x & 63, wid = threadIdx.x >> 6;
    if (lane == 0) { r0[wid] = tm; r1[wid] = ta; }
    __syncthreads();
    if (threadIdx.x == 0) {
        float m = 0.f, a = 0.f;
#pragma unroll
        for (int w = 0; w < 16; ++w) { m += r0[w]; a += r1[w]; }
        out[0] = a / m;
    }
}

extern "C" void kernel_launch(void* const* d_in, const int* in_sizes, int n_in,
                              void* d_out, int out_size, void* d_ws, size_t ws_size,
                              hipStream_t stream) {
    const float* pred = (const float*)d_in[0];
    const float* tgt  = (const float*)d_in[1];
    const float* mask = (const float*)d_in[2];
    float* out = (float*)d_out;
    float* ws  = (float*)d_ws;
    float4* p1s4 = (float4*)ws;
    float*  acc  = ws + WS_ACC_F;

    // No memset needed: every workspace slot (incl. pads) is plain-stored.
    dim3 grid(NBLK), blk(BLOCK);
    pass1<<<grid, blk, 0, stream>>>(pred, tgt, mask, p1s4);
    pass2<<<grid, blk, 0, stream>>>(pred, tgt, p1s4, acc);
    finalize<<<1, 1024, 0, stream>>>(p1s4, acc, out);
}